// Round 3
// baseline (190.901 us; speedup 1.0000x reference)
//
#include <hip/hip_runtime.h>

#define L_IN    4000
#define CIN     512
#define KSZ     16
#define LOUT    31992   // 8 * 3999
#define NQ      3999    // valid q: 0..3998
#define QPB     256     // q positions per block (4 per thread, strided by 64)
#define RSTRIDE 2304    // per-wave reduction stride in floats (>= 9*255+8)

// Block = (b, 256-q tile), 512 threads = 8 waves. Wave w owns ci in [w*64, w*64+64).
// Thread: lane = q%64, computes Q=4 q-positions (q0 + qi*64 + lane), 8 taps each.
// Weights staged once to LDS (32 KB), read via wave-uniform ds_read_b128,
// amortized over 4 q-positions (4x fewer LDS reads per MAC than round 2).
// LDS reused for the cross-wave (ci) reduction with stride-9 padding.
__global__ __launch_bounds__(512, 2)
void dereverb_kernel(const float* __restrict__ x,
                     const float* __restrict__ t60s,
                     const float* __restrict__ kw,
                     float* __restrict__ out)
{
    __shared__ float lds[8 * RSTRIDE];   // 72 KB: weights first, then reduction

    const int b    = blockIdx.y;
    const int q0   = blockIdx.x * QPB;
    const int tid  = threadIdx.x;
    const int lane = tid & 63;
    const int wave = tid >> 6;

    // Per-sample kernel index (uniform): jnp.round = RNE = rintf.
    float t60 = t60s[b & 7];
    int kidx = (int)rintf(t60 * 100.0f) - 10;
    kidx = __builtin_amdgcn_readfirstlane(kidx);
    const float4* wsrc = (const float4*)(kw + (size_t)kidx * (CIN * KSZ));

    // Stage all 512x16 weights: 2048 float4 / 512 threads = 4 each, coalesced.
    #pragma unroll
    for (int i = 0; i < 4; ++i)
        ((float4*)lds)[tid + i * 512] = wsrc[tid + i * 512];
    __syncthreads();

    // 4 q positions per thread; clamp loads to stay in-bounds (q=3998 is last valid,
    // loads touch qc and qc+1 <= 3999).
    const float* xb = x + ((size_t)b * CIN + wave * 64) * L_IN;
    const float* xp[4];
    #pragma unroll
    for (int qi = 0; qi < 4; ++qi) {
        int q  = q0 + qi * 64 + lane;
        int qc = q < NQ - 1 ? q : (NQ - 1);
        xp[qi] = xb + qc;
    }

    const float4* wl = (const float4*)(lds + wave * 64 * KSZ);

    float acc[4][8];
    #pragma unroll
    for (int qi = 0; qi < 4; ++qi)
        #pragma unroll
        for (int r = 0; r < 8; ++r) acc[qi][r] = 0.0f;

    #pragma unroll 2
    for (int ci = 0; ci < 64; ++ci) {
        float x0[4], x1[4];
        #pragma unroll
        for (int qi = 0; qi < 4; ++qi) {
            x0[qi] = xp[qi][0];      // x[b, ci, q]
            x1[qi] = xp[qi][1];      // x[b, ci, q+1]
            xp[qi] += L_IN;
        }
        float4 wv[4];
        wv[0] = wl[0];               // ds_read_b128, wave-uniform -> broadcast
        wv[1] = wl[1];
        wv[2] = wl[2];
        wv[3] = wl[3];
        wl += 4;
        const float* wf = (const float*)wv;
        #pragma unroll
        for (int qi = 0; qi < 4; ++qi)
            #pragma unroll
            for (int r = 0; r < 8; ++r) {
                acc[qi][r] = fmaf(x1[qi], wf[r],     acc[qi][r]);
                acc[qi][r] = fmaf(x0[qi], wf[r + 8], acc[qi][r]);
            }
    }

    // Clamped lanes (q > 3998) contribute nothing.
    #pragma unroll
    for (int qi = 0; qi < 4; ++qi)
        if (q0 + qi * 64 + lane > NQ - 1)
            #pragma unroll
            for (int r = 0; r < 8; ++r) acc[qi][r] = 0.0f;

    // Cross-wave (ci) reduction. Layout: lds[wave*RSTRIDE + 9*q_local + r]
    // (stride 9 -> writes 2-way/free, epilogue reads conflict-free).
    __syncthreads();   // all weight reads done; safe to overwrite
    #pragma unroll
    for (int qi = 0; qi < 4; ++qi) {
        int ql = qi * 64 + lane;
        float* rp = lds + wave * RSTRIDE + 9 * ql;
        #pragma unroll
        for (int r = 0; r < 8; ++r) rp[r] = acc[qi][r];
    }
    __syncthreads();

    // Epilogue: 2048 outputs / 512 threads = 4 each, consecutive tid ->
    // consecutive t (coalesced stores, conflict-free LDS reads).
    const size_t ob = (size_t)b * LOUT + (size_t)q0 * 8;
    #pragma unroll
    for (int k = 0; k < 4; ++k) {
        int tl = k * 512 + tid;
        if (q0 * 8 + tl < LOUT) {    // only last q-tile trims
            int ql = tl >> 3, r = tl & 7;
            float s = 0.0f;
            #pragma unroll
            for (int w = 0; w < 8; ++w)
                s += lds[w * RSTRIDE + 9 * ql + r];
            out[ob + tl] = s;
        }
    }
}

extern "C" void kernel_launch(void* const* d_in, const int* in_sizes, int n_in,
                              void* d_out, int out_size, void* d_ws, size_t ws_size,
                              hipStream_t stream) {
    const float* x    = (const float*)d_in[0];   // (16, 512, 4000)
    const float* t60s = (const float*)d_in[1];   // (8,)
    const float* kw   = (const float*)d_in[2];   // (41, 512, 1, 16)
    float* out = (float*)d_out;                  // (16, 1, 31992)

    dim3 grid((NQ + QPB - 1) / QPB, 16);         // (16, 16)
    dereverb_kernel<<<grid, 512, 0, stream>>>(x, t60s, kw, out);
}